// Round 13
// baseline (132.758 us; speedup 1.0000x reference)
//
#include <hip/hip_runtime.h>
#include <hip/hip_fp16.h>

#define ALPHA 0.3f
#define B_SZ 4096
#define D_SZ 1024
#define CT_STRIDE 132   // multiple of 4: aligned half4 stores, 2-way banks on scans
#define BIGF 3.0e38f
#define SENT_F 60000.0f // fp16-representable sentinel >> any d2 (~4100 max)

typedef __attribute__((ext_vector_type(4))) _Float16 half4;
typedef __attribute__((ext_vector_type(2))) _Float16 half2v;
typedef __attribute__((ext_vector_type(4))) float floatx4;
typedef __attribute__((ext_vector_type(2))) long long2v;

typedef __attribute__((address_space(1))) const void* gas_t;
typedef __attribute__((address_space(3))) void* las_t;

__device__ __forceinline__ float wave_reduce_add(float v) {
#pragma unroll
    for (int off = 32; off; off >>= 1) v += __shfl_xor(v, off);
    return v;
}

// sorted ascending insert of x into best[0..9] (branchless, scalar f32)
__device__ __forceinline__ void insert10(float (&best)[10], float x) {
#pragma unroll
    for (int p = 0; p < 10; ++p) {
        float lo = fminf(best[p], x);
        x = fmaxf(best[p], x);
        best[p] = lo;
    }
}

// packed: two independent sorted-10 lists; lowers to v_pk_min/max_f16
__device__ __forceinline__ void insert10p(half2v (&b)[10], half2v x) {
#pragma unroll
    for (int p = 0; p < 10; ++p) {
        half2v lo = __builtin_elementwise_min(b[p], x);
        x = __builtin_elementwise_max(b[p], x);
        b[p] = lo;
    }
}

// ---------------------------------------------------------------------------
// prep: fp32 -> fp8 e4m3 convert with K-PERMUTED layout (per 64-byte K-chunk,
// 8B granule s -> (s&3)*2 + (s>>2), i.e. order 0,4,1,5,2,6,3,7). This makes
// one 16B LDS unit hold a lane's k-slice for BOTH k-steps of a BK=64 iter,
// so the GEMM reads fragments with ds_read_b128 in the R11-proven
// conflict-free pattern. EXACT fp32 row norms x2/y2 and threshold m[i].
// ---------------------------------------------------------------------------
__global__ void __launch_bounds__(256) prep_kernel(
    const float* __restrict__ in1, const float* __restrict__ in2,
    unsigned char* __restrict__ Xq, unsigned char* __restrict__ Yq,
    float* __restrict__ x2, float* __restrict__ y2, float* __restrict__ mth) {
    int row = blockIdx.x;
    int t = threadIdx.x;
    const float4* a4 = (const float4*)(in1 + (size_t)row * D_SZ);
    const float4* b4 = (const float4*)(in2 + (size_t)row * D_SZ);
    float4 a = a4[t], b = b4[t];
    int ua = 0, ub = 0;
    ua = __builtin_amdgcn_cvt_pk_fp8_f32(a.x, a.y, ua, false);
    ua = __builtin_amdgcn_cvt_pk_fp8_f32(a.z, a.w, ua, true);
    ub = __builtin_amdgcn_cvt_pk_fp8_f32(b.x, b.y, ub, false);
    ub = __builtin_amdgcn_cvt_pk_fp8_f32(b.z, b.w, ub, true);
    // K-permutation: int t covers orig bytes [4t,4t+4). chunk c=t>>4,
    // granule s=(t&15)>>1, half h=t&1; dst int = c*16 + ((s&3)*2+(s>>2))*2 + h.
    int c = t >> 4, s = (t & 15) >> 1, h = t & 1;
    int dst = c * 16 + ((s & 3) * 2 + (s >> 2)) * 2 + h;
    ((int*)(Xq + (size_t)row * D_SZ))[dst] = ua;
    ((int*)(Yq + (size_t)row * D_SZ))[dst] = ub;
    float sa = a.x * a.x + a.y * a.y + a.z * a.z + a.w * a.w;
    float sb = b.x * b.x + b.y * b.y + b.z * b.z + b.w * b.w;
    float d0 = a.x - b.x, d1 = a.y - b.y, d2v = a.z - b.z, d3 = a.w - b.w;
    float sd = d0 * d0 + d1 * d1 + d2v * d2v + d3 * d3;
    sa = wave_reduce_add(sa);
    sb = wave_reduce_add(sb);
    sd = wave_reduce_add(sd);
    __shared__ float red[3][4];
    int wave = t >> 6, lane = t & 63;
    if (lane == 0) { red[0][wave] = sa; red[1][wave] = sb; red[2][wave] = sd; }
    __syncthreads();
    if (t == 0) {
        x2[row] = red[0][0] + red[0][1] + red[0][2] + red[0][3];
        y2[row] = red[1][0] + red[1][1] + red[1][2] + red[1][3];
        mth[row] = sqrtf(red[2][0] + red[2][1] + red[2][2] + red[2][3]) + ALPHA;
    }
}

// ---------------------------------------------------------------------------
// gemm_topk (fp8 e4m3): G = Xq @ Yq^T tile (128x128), BK=64, 16 K-iters.
// K-permuted inputs: LDS unit (r, u) holds both k-steps' slice u; fragment
// read = one ds_read_b128 per mi at R*64 + (q^((R>>1)&3))*16 (the R11
// measured-conflict-free pattern); la.x -> ks=0 MFMA, la.y -> ks=1 MFMA.
// mfma_f32_16x16x32_fp8_fp8. Fused epilogue: Ct fp16 col-major, diag
// pre-clear, packed-fp16 wave-specialized top-10 (waves 0,1 IRR; 2,3 RII).
// ---------------------------------------------------------------------------
__global__ void __launch_bounds__(256) gemm_topk_kernel(
    const unsigned char* __restrict__ Xq, const unsigned char* __restrict__ Yq,
    const float* __restrict__ x2, const float* __restrict__ y2,
    _Float16* __restrict__ CandI, _Float16* __restrict__ CandR) {
    __shared__ __align__(16) unsigned char smem[33792]; // As+Bs 16 KB | Ct 33792 B
    unsigned char* As = smem;          // 128 rows x 64 B
    unsigned char* Bs = smem + 8192;
    int tid = threadIdx.x;
    int wave = tid >> 6, lane = tid & 63;
    int waveR = wave >> 1, waveC = wave & 1;
    // XCD-aware supertile swizzle (measured neutral, kept).
    int id = blockIdx.y * 32 + blockIdx.x;
    int st = id >> 6, w = id & 63;
    int bx = (st & 3) * 8 + (w & 7);
    int by = (st >> 2) * 8 + (w >> 3);
    int q = lane >> 4, mrow = lane & 15;

    floatx4 acc[4][4] = {};

    // Staging: 512 16B-cells per tile per iter; cell c: r=c>>2, u=c&3,
    // source granule g = u ^ ((r>>1)&3) (permuted layout already in Xq/Yq).
    const unsigned char* srcA[2];
    const unsigned char* srcB[2];
    unsigned char* dstA[2];
    unsigned char* dstB[2];
#pragma unroll
    for (int i = 0; i < 2; ++i) {
        int c = i * 256 + tid;
        int r = c >> 2, u = c & 3;
        int g = u ^ ((r >> 1) & 3);
        srcA[i] = Xq + (size_t)(by * 128 + r) * D_SZ + g * 16;
        srcB[i] = Yq + (size_t)(bx * 128 + r) * D_SZ + g * 16;
        dstA[i] = As + (i * 256 + wave * 64) * 16;
        dstB[i] = Bs + (i * 256 + wave * 64) * 16;
    }

    // Reader byte-offsets: one b128 per (row-tile mi), both k-steps inside.
    int aoff[4], boff[4];
#pragma unroll
    for (int mi = 0; mi < 4; ++mi) {
        int Ra = waveR * 64 + mi * 16 + mrow;
        int Rb = waveC * 64 + mi * 16 + mrow;
        aoff[mi] = Ra * 64 + (q ^ ((Ra >> 1) & 3)) * 16;
        boff[mi] = Rb * 64 + (q ^ ((Rb >> 1) & 3)) * 16;
    }

    for (int k0 = 0; k0 < D_SZ; k0 += 64) {
        __syncthreads();
        __builtin_amdgcn_global_load_lds((gas_t)(const void*)(srcA[0] + k0), (las_t)(void*)dstA[0], 16, 0, 0);
        __builtin_amdgcn_global_load_lds((gas_t)(const void*)(srcB[0] + k0), (las_t)(void*)dstB[0], 16, 0, 0);
        __builtin_amdgcn_global_load_lds((gas_t)(const void*)(srcA[1] + k0), (las_t)(void*)dstA[1], 16, 0, 0);
        __builtin_amdgcn_global_load_lds((gas_t)(const void*)(srcB[1] + k0), (las_t)(void*)dstB[1], 16, 0, 0);
        __syncthreads();
        long2v af[4], bf[4];
#pragma unroll
        for (int mi = 0; mi < 4; ++mi) af[mi] = *(const long2v*)&As[aoff[mi]];
#pragma unroll
        for (int ni = 0; ni < 4; ++ni) bf[ni] = *(const long2v*)&Bs[boff[ni]];
#pragma unroll
        for (int mi = 0; mi < 4; ++mi)
#pragma unroll
            for (int ni = 0; ni < 4; ++ni)
                acc[mi][ni] = __builtin_amdgcn_mfma_f32_16x16x32_fp8_fp8(af[mi][0], bf[ni][0], acc[mi][ni], 0, 0, 0);
#pragma unroll
        for (int mi = 0; mi < 4; ++mi)
#pragma unroll
            for (int ni = 0; ni < 4; ++ni)
                acc[mi][ni] = __builtin_amdgcn_mfma_f32_16x16x32_fp8_fp8(af[mi][1], bf[ni][1], acc[mi][ni], 0, 0, 0);
    }
    __syncthreads();  // staging LDS dead; Ct takes over

    // Phase 1: d2 tile -> LDS fp16 col-major: Ct[col*132 + row].
    // C/D layout: col = lane&15, row = q*4 + reg -> 4 consecutive rows = half4.
    _Float16* Ct = (_Float16*)smem;
#pragma unroll
    for (int ni = 0; ni < 4; ++ni) {
        int lc = waveC * 64 + ni * 16 + mrow;
        float y2v = y2[bx * 128 + lc];
#pragma unroll
        for (int mi = 0; mi < 4; ++mi) {
            int lr0 = waveR * 64 + mi * 16 + q * 4;
            int gr0 = by * 128 + lr0;
            floatx4 v = acc[mi][ni];
            half4 hv = {(_Float16)(x2[gr0 + 0] + y2v - 2.0f * v[0]),
                        (_Float16)(x2[gr0 + 1] + y2v - 2.0f * v[1]),
                        (_Float16)(x2[gr0 + 2] + y2v - 2.0f * v[2]),
                        (_Float16)(x2[gr0 + 3] + y2v - 2.0f * v[3])};
            *(half4*)&Ct[lc * CT_STRIDE + lr0] = hv;
        }
    }
    __syncthreads();
    // Diagonal pre-clear (removes all per-element diag masking below).
    if (bx == by && tid < 128) Ct[tid * CT_STRIDE + tid] = (_Float16)SENT_F;
    __syncthreads();

    const half2v sent2 = {(_Float16)SENT_F, (_Float16)SENT_F};

    if (wave < 2) {
        // IRR: lane -> row-pair p (rows 2p, 2p+1), col-half chalf.
        int p = wave * 32 + (lane & 31);     // 0..63
        int chalf = lane >> 5;
        half2v b[10];
#pragma unroll
        for (int i = 0; i < 10; ++i) b[i] = sent2;
#pragma unroll 8
        for (int i = 0; i < 64; ++i) {
            int c = chalf * 64 + i;
            half2v v = *(const half2v*)&Ct[c * CT_STRIDE + 2 * p];
            insert10p(b, v);
        }
        // merge the two col-halves (lanes l <-> l^32)
        half2v t[10];
#pragma unroll
        for (int k = 0; k < 10; ++k)
            t[k] = __builtin_bit_cast(half2v, __shfl_xor(__builtin_bit_cast(int, b[k]), 32));
#pragma unroll
        for (int k = 0; k < 10; ++k) insert10p(b, t[k]);
        if (lane < 32) {
            int grow = by * 128 + 2 * p;
            unsigned int* d0 = (unsigned int*)CandI + ((size_t)grow * 32 + bx) * 5;
            unsigned int* d1 = d0 + 32 * 5;  // row grow+1
#pragma unroll
            for (int k = 0; k < 5; ++k) {
                unsigned int u0 = __builtin_bit_cast(unsigned int, b[2 * k]);
                unsigned int u1 = __builtin_bit_cast(unsigned int, b[2 * k + 1]);
                d0[k] = (u0 & 0xFFFFu) | (u1 << 16);            // low halves = row 2p
                d1[k] = (u0 >> 16) | (u1 & 0xFFFF0000u);        // high halves = row 2p+1
            }
        }
    } else {
        // RII: lane -> full column c; packed halves = even/odd row sub-streams.
        int c = (wave - 2) * 64 + lane;      // 0..127
        half2v b[10];
#pragma unroll
        for (int i = 0; i < 10; ++i) b[i] = sent2;
        const half2v* colp = (const half2v*)&Ct[c * CT_STRIDE];
#pragma unroll 8
        for (int i = 0; i < 64; ++i) insert10p(b, colp[i]);
        // merge even/odd streams: insert the 16-bit-rotated lists (snapshot first)
        half2v sw[10];
#pragma unroll
        for (int k = 0; k < 10; ++k) {
            unsigned int u = __builtin_bit_cast(unsigned int, b[k]);
            sw[k] = __builtin_bit_cast(half2v, (u >> 16) | (u << 16));
        }
#pragma unroll
        for (int k = 0; k < 10; ++k) insert10p(b, sw[k]);
        // low halves of b[0..9] = column top-10
        int gcol = bx * 128 + c;
        unsigned int* d = (unsigned int*)CandR + ((size_t)gcol * 32 + by) * 5;
#pragma unroll
        for (int k = 0; k < 5; ++k) {
            unsigned int u0 = __builtin_bit_cast(unsigned int, b[2 * k]);
            unsigned int u1 = __builtin_bit_cast(unsigned int, b[2 * k + 1]);
            d[k] = (u0 & 0xFFFFu) | (u1 << 16);
        }
    }
}

// ---------------------------------------------------------------------------
// merge: 2048 blocks, ONE row per wave (max TLP; the 10-round reduce is a
// serial latency chain). NO atomics — per-row partials to Srow/Zrow.
// ---------------------------------------------------------------------------
__global__ void __launch_bounds__(256) merge_kernel(
    const _Float16* __restrict__ CandI, const _Float16* __restrict__ CandR,
    const float* __restrict__ mth,
    float* __restrict__ Srow, float* __restrict__ Zrow) {
    int wave = threadIdx.x >> 6, lane = threadIdx.x & 63;
    int r = blockIdx.x * 4 + wave;              // 0..8191
    int row = r & (B_SZ - 1);
    const _Float16* cp = ((r < B_SZ) ? CandI : CandR) + (size_t)row * 320;
    float best[10];
#pragma unroll
    for (int i = 0; i < 10; ++i) best[i] = BIGF;
#pragma unroll
    for (int j = 0; j < 5; ++j) insert10(best, (float)cp[j * 64 + lane]);

    float mrow = mth[row];
    float s = 0.f, z = 0.f;
#pragma unroll
    for (int round = 0; round < 10; ++round) {
        float v0 = best[0];
        float g = v0;
#pragma unroll
        for (int off = 32; off; off >>= 1) g = fminf(g, __shfl_xor(g, off));
        unsigned long long ball = __ballot(v0 == g);
        int leader = __ffsll(ball) - 1;
        if (lane == leader) {
#pragma unroll
            for (int p = 0; p < 9; ++p) best[p] = best[p + 1];
            best[9] = BIGF;
        }
        float d = sqrtf(fmaxf(g, 0.f));
        float c = fmaxf(mrow - d, 0.f);
        s += c;
        z += (c == 0.f) ? 1.f : 0.f;
    }
    if (lane == 0) { Srow[r] = s; Zrow[r] = z; }
}

// ---------------------------------------------------------------------------
// finalize: reduce per-row partials -> [loss_irr, loss_rii, bad_irr, bad_rii]
// Srow/Zrow are 8192 floats each = 2048 float4: [0,1024) IRR, [1024,2048) RII.
// ---------------------------------------------------------------------------
__global__ void __launch_bounds__(256) finalize_kernel(
    const float* __restrict__ Srow, const float* __restrict__ Zrow,
    float* __restrict__ out) {
    __shared__ float red[256][4];
    int t = threadIdx.x;
    float s0 = 0, s1 = 0, z0 = 0, z1 = 0;
#pragma unroll
    for (int k = 0; k < 8; ++k) {
        int i = k * 256 + t;
        float4 sv = ((const float4*)Srow)[i];
        float4 zv = ((const float4*)Zrow)[i];
        float ss = sv.x + sv.y + sv.z + sv.w;
        float zz = zv.x + zv.y + zv.z + zv.w;
        if (i < 1024) { s0 += ss; z0 += zz; } else { s1 += ss; z1 += zz; }
    }
    red[t][0] = s0; red[t][1] = s1; red[t][2] = z0; red[t][3] = z1;
    __syncthreads();
    for (int off = 128; off > 0; off >>= 1) {
        if (t < off) {
#pragma unroll
            for (int j = 0; j < 4; ++j) red[t][j] += red[t + off][j];
        }
        __syncthreads();
    }
    if (t == 0) {
        const float inv = 1.0f / (float)(B_SZ * 10);
        out[0] = red[0][0] * inv;  // loss_irr
        out[1] = red[0][1] * inv;  // loss_rii
        out[2] = red[0][2] * inv;  // bad_irr
        out[3] = red[0][3] * inv;  // bad_rii
    }
}

// ---------------------------------------------------------------------------
extern "C" void kernel_launch(void* const* d_in, const int* in_sizes, int n_in,
                              void* d_out, int out_size, void* d_ws, size_t ws_size,
                              hipStream_t stream) {
    const float* in1 = (const float*)d_in[0];
    const float* in2 = (const float*)d_in[1];
    float* out = (float*)d_out;

    char* ws = (char*)d_ws;
    const size_t MB = 1024 * 1024;
    unsigned char* Xq = (unsigned char*)(ws);        // 4 MiB
    unsigned char* Yq = (unsigned char*)(ws + 4 * MB);  // 4 MiB
    _Float16* CandI = (_Float16*)(ws + 8 * MB);      // 4096*32*10*2B = 2.62 MB
    _Float16* CandR = (_Float16*)(ws + 11 * MB);     // 2.62 MB
    float* x2   = (float*)(ws + 14 * MB);
    float* y2   = x2 + B_SZ;
    float* mth  = y2 + B_SZ;
    float* Srow = mth + B_SZ;                        // 8192 floats
    float* Zrow = Srow + 2 * B_SZ;                   // 8192 floats
    const size_t needed = 14 * MB + (size_t)(3 * B_SZ + 4 * B_SZ) * sizeof(float);
    if (ws_size < needed) return;

    hipLaunchKernelGGL(prep_kernel, dim3(B_SZ), dim3(256), 0, stream,
                       in1, in2, Xq, Yq, x2, y2, mth);
    hipLaunchKernelGGL(gemm_topk_kernel, dim3(32, 32), dim3(256), 0, stream,
                       Xq, Yq, x2, y2, CandI, CandR);
    hipLaunchKernelGGL(merge_kernel, dim3(2048), dim3(256), 0, stream,
                       CandI, CandR, mth, Srow, Zrow);
    hipLaunchKernelGGL(finalize_kernel, dim3(1), dim3(256), 0, stream,
                       Srow, Zrow, out);
}